// Round 4
// baseline (2281.816 us; speedup 1.0000x reference)
//
#include <hip/hip_runtime.h>
#include <hip/hip_bf16.h>

// DigitCapsules dynamic routing. Round-4 design:
//  - Round-3 structure (one block/batch, 512 threads, bf16-packed transposed W)
//    PLUS full unrolling of every class loop. Round-3's runtime c-loops made
//    blog[j][c] dynamically indexed -> scratch spill (1.3 GB FETCH+WRITE,
//    VGPR_Count=128). With #pragma unroll all array indices are compile-time
//    constants -> everything lives in VGPRs.
//  - Unrolled body also exposes ~160 independent global_load_dwordx4 per
//    phase: ILP hides L2 latency even at 8 waves/CU.

#define NCLS   10
#define NCAPS  1152
#define KDO    16
#define NIT    3
#define TPB    512
#define NJ     3
#define NWAVE  (TPB / 64)

static __device__ __forceinline__ unsigned short f2bf(float f) {
    __hip_bfloat16 h = __float2bfloat16(f);
    return *reinterpret_cast<unsigned short*>(&h);
}

// Wt[c][d][i] : uint4 holding bf16 W[c,i,0,d,k] for k=0..7
__global__ __launch_bounds__(256)
void pack_W_bf16(const float4* __restrict__ W4, uint4* __restrict__ Wt) {
    int tid = blockIdx.x * blockDim.x + threadIdx.x;   // (c*NCAPS+i)*KDO + d
    if (tid >= NCLS * NCAPS * KDO) return;
    int d = tid & 15;
    int rest = tid >> 4;
    int i = rest % NCAPS;
    int c = rest / NCAPS;
    float4 a = W4[2 * tid];
    float4 b = W4[2 * tid + 1];
    uint4 o;
    o.x = (unsigned)f2bf(a.x) | ((unsigned)f2bf(a.y) << 16);
    o.y = (unsigned)f2bf(a.z) | ((unsigned)f2bf(a.w) << 16);
    o.z = (unsigned)f2bf(b.x) | ((unsigned)f2bf(b.y) << 16);
    o.w = (unsigned)f2bf(b.z) | ((unsigned)f2bf(b.w) << 16);
    Wt[(size_t)(c * KDO + d) * NCAPS + i] = o;
}

static __device__ __forceinline__ float dot_bf8(uint4 r, const float4& x0, const float4& x1) {
    float e0 = __uint_as_float(r.x << 16);
    float e1 = __uint_as_float(r.x & 0xffff0000u);
    float e2 = __uint_as_float(r.y << 16);
    float e3 = __uint_as_float(r.y & 0xffff0000u);
    float e4 = __uint_as_float(r.z << 16);
    float e5 = __uint_as_float(r.z & 0xffff0000u);
    float e6 = __uint_as_float(r.w << 16);
    float e7 = __uint_as_float(r.w & 0xffff0000u);
    return e0 * x0.x + e1 * x0.y + e2 * x0.z + e3 * x0.w
         + e4 * x1.x + e5 * x1.y + e6 * x1.z + e7 * x1.w;
}

static __device__ __forceinline__ float dot_f8(const float4* W4, size_t row2,
                                               const float4& x0, const float4& x1) {
    float4 w0 = W4[row2];
    float4 w1 = W4[row2 + 1];
    return w0.x * x0.x + w0.y * x0.y + w0.z * x0.z + w0.w * x0.w
         + w1.x * x1.x + w1.y * x1.y + w1.z * x1.z + w1.w * x1.w;
}

template <bool TR>
__global__ __launch_bounds__(TPB, 2)
void caps_routing(const uint4* __restrict__ Wt,   // TR path: [C][KDO][I] bf16x8
                  const float4* __restrict__ W4,  // fallback: [C][I][KDO][8] fp32
                  const float* __restrict__ x,    // [B, I, 8]
                  float* __restrict__ out)        // [B, C, 1, KDO]
{
    const int b    = blockIdx.x;
    const int t    = threadIdx.x;
    const int lane = t & 63;
    const int wave = t >> 6;

    __shared__ float v_prev[NCLS * KDO];             // 640 B
    __shared__ float red[NCLS * NWAVE * KDO];        // 5120 B

    // ---- x[b, ii, :] in registers ----
    float4 xr[NJ][2];
    const float4* x4 = reinterpret_cast<const float4*>(x) + (size_t)b * NCAPS * 2;
    #pragma unroll
    for (int j = 0; j < NJ; ++j) {
        int ii = t + TPB * j;
        if (ii < NCAPS) {
            xr[j][0] = x4[2 * ii];
            xr[j][1] = x4[2 * ii + 1];
        }
    }

    float blog[NJ][NCLS];
    #pragma unroll
    for (int j = 0; j < NJ; ++j)
        #pragma unroll
        for (int c = 0; c < NCLS; ++c)
            blog[j][c] = 0.f;

    for (int it = 0; it < NIT; ++it) {
        // ---- Phase A: blog[ii][c] += <u_hat[c,ii,:], v_prev[c,:]> ----
        if (it > 0) {
            #pragma unroll
            for (int c = 0; c < NCLS; ++c) {
                float vp[KDO];
                #pragma unroll
                for (int d = 0; d < KDO; ++d)
                    vp[d] = v_prev[c * KDO + d];
                #pragma unroll
                for (int j = 0; j < NJ; ++j) {
                    int ii = t + TPB * j;
                    if (ii < NCAPS) {
                        float a = 0.f;
                        #pragma unroll
                        for (int d = 0; d < KDO; ++d) {
                            float u = TR ? dot_bf8(Wt[(size_t)(c * KDO + d) * NCAPS + ii],
                                                   xr[j][0], xr[j][1])
                                         : dot_f8(W4, ((size_t)(c * NCAPS + ii) * KDO + d) * 2,
                                                  xr[j][0], xr[j][1]);
                            a += u * vp[d];
                        }
                        blog[j][c] += a;
                    }
                }
            }
        }

        // ---- Phase B: softmax over classes (thread-local, registers) ----
        float sm[NJ], sid[NJ];
        #pragma unroll
        for (int j = 0; j < NJ; ++j) {
            int ii = t + TPB * j;
            if (ii < NCAPS) {
                float m = blog[j][0];
                #pragma unroll
                for (int c = 1; c < NCLS; ++c) m = fmaxf(m, blog[j][c]);
                float den = 0.f;
                #pragma unroll
                for (int c = 0; c < NCLS; ++c) den += __expf(blog[j][c] - m);
                sm[j]  = m;
                sid[j] = 1.f / den;
            }
        }

        // ---- Phase C: s[c,:] = sum_ii softmax_c(blog) * u_hat[c,ii,:] ----
        #pragma unroll
        for (int c = 0; c < NCLS; ++c) {
            float acc[KDO];
            #pragma unroll
            for (int d = 0; d < KDO; ++d) acc[d] = 0.f;

            #pragma unroll
            for (int j = 0; j < NJ; ++j) {
                int ii = t + TPB * j;
                if (ii < NCAPS) {
                    float wgt = __expf(blog[j][c] - sm[j]) * sid[j];
                    #pragma unroll
                    for (int d = 0; d < KDO; ++d) {
                        float u = TR ? dot_bf8(Wt[(size_t)(c * KDO + d) * NCAPS + ii],
                                               xr[j][0], xr[j][1])
                                     : dot_f8(W4, ((size_t)(c * NCAPS + ii) * KDO + d) * 2,
                                              xr[j][0], xr[j][1]);
                        acc[d] += wgt * u;
                    }
                }
            }

            #pragma unroll
            for (int d = 0; d < KDO; ++d) {
                float v = acc[d];
                v += __shfl_xor(v, 32, 64);
                v += __shfl_xor(v, 16, 64);
                v += __shfl_xor(v,  8, 64);
                v += __shfl_xor(v,  4, 64);
                v += __shfl_xor(v,  2, 64);
                v += __shfl_xor(v,  1, 64);
                if (lane == 0) red[(c * NWAVE + wave) * KDO + d] = v;
            }
        }
        __syncthreads();

        // ---- squash + broadcast: threads 0..159 (c = t/16, d = t%16) ----
        if (t < NCLS * KDO) {
            int c = t >> 4;
            int d = t & 15;
            float s = 0.f;
            #pragma unroll
            for (int w = 0; w < NWAVE; ++w)
                s += red[(c * NWAVE + w) * KDO + d];
            float nsq = s * s;
            nsq += __shfl_xor(nsq, 8, 16);
            nsq += __shfl_xor(nsq, 4, 16);
            nsq += __shfl_xor(nsq, 2, 16);
            nsq += __shfl_xor(nsq, 1, 16);
            float scale = sqrtf(nsq) / (1.f + nsq);      // (nsq/(1+nsq))/sqrt(nsq)
            float vv = s * scale;
            v_prev[t] = vv;
            if (it == NIT - 1)
                out[(size_t)b * NCLS * KDO + t] = vv;
        }
        __syncthreads();
    }
}

extern "C" void kernel_launch(void* const* d_in, const int* in_sizes, int n_in,
                              void* d_out, int out_size, void* d_ws, size_t ws_size,
                              hipStream_t stream) {
    const float* x = (const float*)d_in[0];              // [256, 1152, 8] fp32
    const float4* W4 = (const float4*)d_in[1];           // [10, 1152, 1, 16, 8] fp32
    float* out = (float*)d_out;                          // [256, 10, 1, 16] fp32
    (void)in_sizes; (void)n_in; (void)out_size;

    const int B = 256;
    const size_t wt_bytes = (size_t)NCLS * KDO * NCAPS * sizeof(uint4);  // 2.95 MB
    if (ws_size >= wt_bytes) {
        uint4* Wt = (uint4*)d_ws;
        int total = NCLS * NCAPS * KDO;
        pack_W_bf16<<<dim3((total + 255) / 256), dim3(256), 0, stream>>>(W4, Wt);
        caps_routing<true><<<dim3(B), dim3(TPB), 0, stream>>>(Wt, W4, x, out);
    } else {
        caps_routing<false><<<dim3(B), dim3(TPB), 0, stream>>>(nullptr, W4, x, out);
    }
}

// Round 5
// 2044.178 us; speedup vs baseline: 1.1163x; 1.1163x over previous
//
#include <hip/hip_runtime.h>
#include <hip/hip_bf16.h>

// DigitCapsules dynamic routing. Round-5 design:
//  - Execution config EXACTLY as round 1 (the only proven no-spill config):
//    one block per batch element, TPB=256, __launch_bounds__(256,2), NJ=5.
//    Empirical launch-bounds decode across R1-R4: (256,2)->cap 256 regs OK;
//    (512,2)->cap 128 -> spill; (1024,4)->cap 64 -> disaster. Never request
//    >=512 threads with multiplier >=2 on this kernel.
//  - Data layout as round 3: W packed to bf16, transposed Wt[c][d][i] uint4
//    (8 bf16 k-row per (c,i,d)); lane stride 16 B -> coalesced, half the
//    bytes and half the load instructions of fp32.
//  - #pragma unroll on all class loops so blog/acc stay statically indexed
//    (round-3's bf16 bodies defeated auto-unroll -> dynamic index -> spill).

#define NCLS   10
#define NCAPS  1152
#define KDO    16
#define NIT    3
#define TPB    256
#define NJ     5
#define NWAVE  (TPB / 64)

static __device__ __forceinline__ unsigned short f2bf(float f) {
    __hip_bfloat16 h = __float2bfloat16(f);
    return *reinterpret_cast<unsigned short*>(&h);
}

// Wt[c][d][i] : uint4 holding bf16 W[c,i,0,d,k] for k=0..7
__global__ __launch_bounds__(256)
void pack_W_bf16(const float4* __restrict__ W4, uint4* __restrict__ Wt) {
    int tid = blockIdx.x * blockDim.x + threadIdx.x;   // (c*NCAPS+i)*KDO + d
    if (tid >= NCLS * NCAPS * KDO) return;
    int d = tid & 15;
    int rest = tid >> 4;
    int i = rest % NCAPS;
    int c = rest / NCAPS;
    float4 a = W4[2 * tid];
    float4 b = W4[2 * tid + 1];
    uint4 o;
    o.x = (unsigned)f2bf(a.x) | ((unsigned)f2bf(a.y) << 16);
    o.y = (unsigned)f2bf(a.z) | ((unsigned)f2bf(a.w) << 16);
    o.z = (unsigned)f2bf(b.x) | ((unsigned)f2bf(b.y) << 16);
    o.w = (unsigned)f2bf(b.z) | ((unsigned)f2bf(b.w) << 16);
    Wt[(size_t)(c * KDO + d) * NCAPS + i] = o;
}

static __device__ __forceinline__ float dot_bf8(uint4 r, const float4& x0, const float4& x1) {
    float e0 = __uint_as_float(r.x << 16);
    float e1 = __uint_as_float(r.x & 0xffff0000u);
    float e2 = __uint_as_float(r.y << 16);
    float e3 = __uint_as_float(r.y & 0xffff0000u);
    float e4 = __uint_as_float(r.z << 16);
    float e5 = __uint_as_float(r.z & 0xffff0000u);
    float e6 = __uint_as_float(r.w << 16);
    float e7 = __uint_as_float(r.w & 0xffff0000u);
    return e0 * x0.x + e1 * x0.y + e2 * x0.z + e3 * x0.w
         + e4 * x1.x + e5 * x1.y + e6 * x1.z + e7 * x1.w;
}

static __device__ __forceinline__ float dot_f8(const float4* W4, size_t row2,
                                               const float4& x0, const float4& x1) {
    float4 w0 = W4[row2];
    float4 w1 = W4[row2 + 1];
    return w0.x * x0.x + w0.y * x0.y + w0.z * x0.z + w0.w * x0.w
         + w1.x * x1.x + w1.y * x1.y + w1.z * x1.z + w1.w * x1.w;
}

template <bool TR>
__global__ __launch_bounds__(TPB, 2)
void caps_routing(const uint4* __restrict__ Wt,   // TR path: [C][KDO][I] bf16x8
                  const float4* __restrict__ W4,  // fallback: [C][I][KDO][8] fp32
                  const float* __restrict__ x,    // [B, I, 8]
                  float* __restrict__ out)        // [B, C, 1, KDO]
{
    const int b    = blockIdx.x;
    const int t    = threadIdx.x;
    const int lane = t & 63;
    const int wave = t >> 6;

    __shared__ float v_prev[NCLS * KDO];             // 640 B
    __shared__ float red[NCLS * NWAVE * KDO];        // 2560 B

    // ---- x[b, ii, :] in registers (coalesced float4) ----
    float4 xr[NJ][2];
    const float4* x4 = reinterpret_cast<const float4*>(x) + (size_t)b * NCAPS * 2;
    #pragma unroll
    for (int j = 0; j < NJ; ++j) {
        int ii = t + TPB * j;
        if (ii < NCAPS) {
            xr[j][0] = x4[2 * ii];
            xr[j][1] = x4[2 * ii + 1];
        }
    }

    float blog[NJ][NCLS];
    #pragma unroll
    for (int j = 0; j < NJ; ++j)
        #pragma unroll
        for (int c = 0; c < NCLS; ++c)
            blog[j][c] = 0.f;

    for (int it = 0; it < NIT; ++it) {
        // ---- Phase A: blog[ii][c] += <u_hat[c,ii,:], v_prev[c,:]> ----
        if (it > 0) {
            #pragma unroll
            for (int c = 0; c < NCLS; ++c) {
                float vp[KDO];
                #pragma unroll
                for (int d = 0; d < KDO; ++d)
                    vp[d] = v_prev[c * KDO + d];
                #pragma unroll
                for (int j = 0; j < NJ; ++j) {
                    int ii = t + TPB * j;
                    if (ii < NCAPS) {
                        float a = 0.f;
                        #pragma unroll
                        for (int d = 0; d < KDO; ++d) {
                            float u = TR ? dot_bf8(Wt[(size_t)(c * KDO + d) * NCAPS + ii],
                                                   xr[j][0], xr[j][1])
                                         : dot_f8(W4, ((size_t)(c * NCAPS + ii) * KDO + d) * 2,
                                                  xr[j][0], xr[j][1]);
                            a += u * vp[d];
                        }
                        blog[j][c] += a;
                    }
                }
            }
        }

        // ---- Phase B: softmax over classes (thread-local, registers) ----
        float sm[NJ], sid[NJ];
        #pragma unroll
        for (int j = 0; j < NJ; ++j) {
            int ii = t + TPB * j;
            if (ii < NCAPS) {
                float m = blog[j][0];
                #pragma unroll
                for (int c = 1; c < NCLS; ++c) m = fmaxf(m, blog[j][c]);
                float den = 0.f;
                #pragma unroll
                for (int c = 0; c < NCLS; ++c) den += __expf(blog[j][c] - m);
                sm[j]  = m;
                sid[j] = 1.f / den;
            }
        }

        // ---- Phase C: s[c,:] = sum_ii softmax_c(blog) * u_hat[c,ii,:] ----
        #pragma unroll
        for (int c = 0; c < NCLS; ++c) {
            float acc[KDO];
            #pragma unroll
            for (int d = 0; d < KDO; ++d) acc[d] = 0.f;

            #pragma unroll
            for (int j = 0; j < NJ; ++j) {
                int ii = t + TPB * j;
                if (ii < NCAPS) {
                    float wgt = __expf(blog[j][c] - sm[j]) * sid[j];
                    #pragma unroll
                    for (int d = 0; d < KDO; ++d) {
                        float u = TR ? dot_bf8(Wt[(size_t)(c * KDO + d) * NCAPS + ii],
                                               xr[j][0], xr[j][1])
                                     : dot_f8(W4, ((size_t)(c * NCAPS + ii) * KDO + d) * 2,
                                              xr[j][0], xr[j][1]);
                        acc[d] += wgt * u;
                    }
                }
            }

            #pragma unroll
            for (int d = 0; d < KDO; ++d) {
                float v = acc[d];
                v += __shfl_xor(v, 32, 64);
                v += __shfl_xor(v, 16, 64);
                v += __shfl_xor(v,  8, 64);
                v += __shfl_xor(v,  4, 64);
                v += __shfl_xor(v,  2, 64);
                v += __shfl_xor(v,  1, 64);
                if (lane == 0) red[(c * NWAVE + wave) * KDO + d] = v;
            }
        }
        __syncthreads();

        // ---- squash + broadcast: threads 0..159 (c = t/16, d = t%16) ----
        if (t < NCLS * KDO) {
            int c = t >> 4;
            int d = t & 15;
            float s = 0.f;
            #pragma unroll
            for (int w = 0; w < NWAVE; ++w)
                s += red[(c * NWAVE + w) * KDO + d];
            float nsq = s * s;
            nsq += __shfl_xor(nsq, 8, 16);
            nsq += __shfl_xor(nsq, 4, 16);
            nsq += __shfl_xor(nsq, 2, 16);
            nsq += __shfl_xor(nsq, 1, 16);
            float scale = sqrtf(nsq) / (1.f + nsq);      // (nsq/(1+nsq))/sqrt(nsq)
            float vv = s * scale;
            v_prev[t] = vv;
            if (it == NIT - 1)
                out[(size_t)b * NCLS * KDO + t] = vv;
        }
        __syncthreads();
    }
}

extern "C" void kernel_launch(void* const* d_in, const int* in_sizes, int n_in,
                              void* d_out, int out_size, void* d_ws, size_t ws_size,
                              hipStream_t stream) {
    const float* x = (const float*)d_in[0];              // [256, 1152, 8] fp32
    const float4* W4 = (const float4*)d_in[1];           // [10, 1152, 1, 16, 8] fp32
    float* out = (float*)d_out;                          // [256, 10, 1, 16] fp32
    (void)in_sizes; (void)n_in; (void)out_size;

    const int B = 256;
    const size_t wt_bytes = (size_t)NCLS * KDO * NCAPS * sizeof(uint4);  // 2.95 MB
    if (ws_size >= wt_bytes) {
        uint4* Wt = (uint4*)d_ws;
        int total = NCLS * NCAPS * KDO;
        pack_W_bf16<<<dim3((total + 255) / 256), dim3(256), 0, stream>>>(W4, Wt);
        caps_routing<true><<<dim3(B), dim3(TPB), 0, stream>>>(Wt, W4, x, out);
    } else {
        caps_routing<false><<<dim3(B), dim3(TPB), 0, stream>>>(nullptr, W4, x, out);
    }
}

// Round 6
// 1197.835 us; speedup vs baseline: 1.9050x; 1.7066x over previous
//
#include <hip/hip_runtime.h>
#include <hip/hip_bf16.h>

// DigitCapsules dynamic routing. Round-6 design:
//  - IDENTICAL to round 5 except __launch_bounds__(256, 1) on the routing
//    kernel. Empirical launch-bounds law on this compiler (fit to R1-R5):
//      VGPR cap = 256 / second_arg.
//    (1024,4)->64, (512,2)->128, (256,2)->128 (R1's fp32 fit in 124 by luck;
//    bf16 versions need ~140-180 -> every (x,2) round spilled ~0.5-2 GB to
//    scratch). Second arg = 1 -> cap 256, which this kernel's ~160-reg state
//    fits comfortably.
//  - Structure: one block per batch element, TPB=256, thread t owns capsules
//    ii = t + 256*j (j=0..4); x and blog register-resident; W bf16-packed +
//    transposed to Wt[c][d][i] uint4 (lane stride 16 B, coalesced, half the
//    bytes of fp32); class loops force-unrolled so all indexing is static.

#define NCLS   10
#define NCAPS  1152
#define KDO    16
#define NIT    3
#define TPB    256
#define NJ     5
#define NWAVE  (TPB / 64)

static __device__ __forceinline__ unsigned short f2bf(float f) {
    __hip_bfloat16 h = __float2bfloat16(f);
    return *reinterpret_cast<unsigned short*>(&h);
}

// Wt[c][d][i] : uint4 holding bf16 W[c,i,0,d,k] for k=0..7
__global__ __launch_bounds__(256)
void pack_W_bf16(const float4* __restrict__ W4, uint4* __restrict__ Wt) {
    int tid = blockIdx.x * blockDim.x + threadIdx.x;   // (c*NCAPS+i)*KDO + d
    if (tid >= NCLS * NCAPS * KDO) return;
    int d = tid & 15;
    int rest = tid >> 4;
    int i = rest % NCAPS;
    int c = rest / NCAPS;
    float4 a = W4[2 * tid];
    float4 b = W4[2 * tid + 1];
    uint4 o;
    o.x = (unsigned)f2bf(a.x) | ((unsigned)f2bf(a.y) << 16);
    o.y = (unsigned)f2bf(a.z) | ((unsigned)f2bf(a.w) << 16);
    o.z = (unsigned)f2bf(b.x) | ((unsigned)f2bf(b.y) << 16);
    o.w = (unsigned)f2bf(b.z) | ((unsigned)f2bf(b.w) << 16);
    Wt[(size_t)(c * KDO + d) * NCAPS + i] = o;
}

static __device__ __forceinline__ float dot_bf8(uint4 r, const float4& x0, const float4& x1) {
    float e0 = __uint_as_float(r.x << 16);
    float e1 = __uint_as_float(r.x & 0xffff0000u);
    float e2 = __uint_as_float(r.y << 16);
    float e3 = __uint_as_float(r.y & 0xffff0000u);
    float e4 = __uint_as_float(r.z << 16);
    float e5 = __uint_as_float(r.z & 0xffff0000u);
    float e6 = __uint_as_float(r.w << 16);
    float e7 = __uint_as_float(r.w & 0xffff0000u);
    return e0 * x0.x + e1 * x0.y + e2 * x0.z + e3 * x0.w
         + e4 * x1.x + e5 * x1.y + e6 * x1.z + e7 * x1.w;
}

static __device__ __forceinline__ float dot_f8(const float4* W4, size_t row2,
                                               const float4& x0, const float4& x1) {
    float4 w0 = W4[row2];
    float4 w1 = W4[row2 + 1];
    return w0.x * x0.x + w0.y * x0.y + w0.z * x0.z + w0.w * x0.w
         + w1.x * x1.x + w1.y * x1.y + w1.z * x1.z + w1.w * x1.w;
}

template <bool TR>
__global__ __launch_bounds__(TPB, 1)      // second arg 1 -> VGPR cap 256 (see header)
void caps_routing(const uint4* __restrict__ Wt,   // TR path: [C][KDO][I] bf16x8
                  const float4* __restrict__ W4,  // fallback: [C][I][KDO][8] fp32
                  const float* __restrict__ x,    // [B, I, 8]
                  float* __restrict__ out)        // [B, C, 1, KDO]
{
    const int b    = blockIdx.x;
    const int t    = threadIdx.x;
    const int lane = t & 63;
    const int wave = t >> 6;

    __shared__ float v_prev[NCLS * KDO];             // 640 B
    __shared__ float red[NCLS * NWAVE * KDO];        // 2560 B

    // ---- x[b, ii, :] in registers (coalesced float4) ----
    float4 xr[NJ][2];
    const float4* x4 = reinterpret_cast<const float4*>(x) + (size_t)b * NCAPS * 2;
    #pragma unroll
    for (int j = 0; j < NJ; ++j) {
        int ii = t + TPB * j;
        if (ii < NCAPS) {
            xr[j][0] = x4[2 * ii];
            xr[j][1] = x4[2 * ii + 1];
        }
    }

    float blog[NJ][NCLS];
    #pragma unroll
    for (int j = 0; j < NJ; ++j)
        #pragma unroll
        for (int c = 0; c < NCLS; ++c)
            blog[j][c] = 0.f;

    for (int it = 0; it < NIT; ++it) {
        // ---- Phase A: blog[ii][c] += <u_hat[c,ii,:], v_prev[c,:]> ----
        if (it > 0) {
            #pragma unroll
            for (int c = 0; c < NCLS; ++c) {
                float vp[KDO];
                #pragma unroll
                for (int d = 0; d < KDO; ++d)
                    vp[d] = v_prev[c * KDO + d];
                #pragma unroll
                for (int j = 0; j < NJ; ++j) {
                    int ii = t + TPB * j;
                    if (ii < NCAPS) {
                        float a = 0.f;
                        #pragma unroll
                        for (int d = 0; d < KDO; ++d) {
                            float u = TR ? dot_bf8(Wt[(size_t)(c * KDO + d) * NCAPS + ii],
                                                   xr[j][0], xr[j][1])
                                         : dot_f8(W4, ((size_t)(c * NCAPS + ii) * KDO + d) * 2,
                                                  xr[j][0], xr[j][1]);
                            a += u * vp[d];
                        }
                        blog[j][c] += a;
                    }
                }
            }
        }

        // ---- Phase B: softmax over classes (thread-local, registers) ----
        float sm[NJ], sid[NJ];
        #pragma unroll
        for (int j = 0; j < NJ; ++j) {
            int ii = t + TPB * j;
            if (ii < NCAPS) {
                float m = blog[j][0];
                #pragma unroll
                for (int c = 1; c < NCLS; ++c) m = fmaxf(m, blog[j][c]);
                float den = 0.f;
                #pragma unroll
                for (int c = 0; c < NCLS; ++c) den += __expf(blog[j][c] - m);
                sm[j]  = m;
                sid[j] = 1.f / den;
            }
        }

        // ---- Phase C: s[c,:] = sum_ii softmax_c(blog) * u_hat[c,ii,:] ----
        #pragma unroll
        for (int c = 0; c < NCLS; ++c) {
            float acc[KDO];
            #pragma unroll
            for (int d = 0; d < KDO; ++d) acc[d] = 0.f;

            #pragma unroll
            for (int j = 0; j < NJ; ++j) {
                int ii = t + TPB * j;
                if (ii < NCAPS) {
                    float wgt = __expf(blog[j][c] - sm[j]) * sid[j];
                    #pragma unroll
                    for (int d = 0; d < KDO; ++d) {
                        float u = TR ? dot_bf8(Wt[(size_t)(c * KDO + d) * NCAPS + ii],
                                               xr[j][0], xr[j][1])
                                     : dot_f8(W4, ((size_t)(c * NCAPS + ii) * KDO + d) * 2,
                                              xr[j][0], xr[j][1]);
                        acc[d] += wgt * u;
                    }
                }
            }

            #pragma unroll
            for (int d = 0; d < KDO; ++d) {
                float v = acc[d];
                v += __shfl_xor(v, 32, 64);
                v += __shfl_xor(v, 16, 64);
                v += __shfl_xor(v,  8, 64);
                v += __shfl_xor(v,  4, 64);
                v += __shfl_xor(v,  2, 64);
                v += __shfl_xor(v,  1, 64);
                if (lane == 0) red[(c * NWAVE + wave) * KDO + d] = v;
            }
        }
        __syncthreads();

        // ---- squash + broadcast: threads 0..159 (c = t/16, d = t%16) ----
        if (t < NCLS * KDO) {
            int c = t >> 4;
            int d = t & 15;
            float s = 0.f;
            #pragma unroll
            for (int w = 0; w < NWAVE; ++w)
                s += red[(c * NWAVE + w) * KDO + d];
            float nsq = s * s;
            nsq += __shfl_xor(nsq, 8, 16);
            nsq += __shfl_xor(nsq, 4, 16);
            nsq += __shfl_xor(nsq, 2, 16);
            nsq += __shfl_xor(nsq, 1, 16);
            float scale = sqrtf(nsq) / (1.f + nsq);      // (nsq/(1+nsq))/sqrt(nsq)
            float vv = s * scale;
            v_prev[t] = vv;
            if (it == NIT - 1)
                out[(size_t)b * NCLS * KDO + t] = vv;
        }
        __syncthreads();
    }
}

extern "C" void kernel_launch(void* const* d_in, const int* in_sizes, int n_in,
                              void* d_out, int out_size, void* d_ws, size_t ws_size,
                              hipStream_t stream) {
    const float* x = (const float*)d_in[0];              // [256, 1152, 8] fp32
    const float4* W4 = (const float4*)d_in[1];           // [10, 1152, 1, 16, 8] fp32
    float* out = (float*)d_out;                          // [256, 10, 1, 16] fp32
    (void)in_sizes; (void)n_in; (void)out_size;

    const int B = 256;
    const size_t wt_bytes = (size_t)NCLS * KDO * NCAPS * sizeof(uint4);  // 2.95 MB
    if (ws_size >= wt_bytes) {
        uint4* Wt = (uint4*)d_ws;
        int total = NCLS * NCAPS * KDO;
        pack_W_bf16<<<dim3((total + 255) / 256), dim3(256), 0, stream>>>(W4, Wt);
        caps_routing<true><<<dim3(B), dim3(TPB), 0, stream>>>(Wt, W4, x, out);
    } else {
        caps_routing<false><<<dim3(B), dim3(TPB), 0, stream>>>(nullptr, W4, x, out);
    }
}

// Round 7
// 708.098 us; speedup vs baseline: 3.2225x; 1.6916x over previous
//
#include <hip/hip_runtime.h>

// DigitCapsules dynamic routing. Round-7 design:
//  - SPILL FIX (the R2-R6 saga): blog moves to LDS. blog is thread-private
//    (each (i,c) read/written only by its owner thread) so LDS needs no new
//    syncs, and dynamic class indexing is free there. Class loops are FORCED
//    runtime (#pragma unroll 1): small body, ~100 live regs, nothing for the
//    scheduler to blow up. R4-R6 proved register-resident blog + full unroll
//    needs >256 VGPRs on this compiler (416-2068 MB scratch traffic).
//  - W packed to f16 (not bf16) in transposed layout Wt[c][d][i] uint4
//    (8 f16 k-values): coalesced 16 B lane stride, half of fp32 bytes, and
//    v_dot2_f32_f16 (__builtin_amdgcn_fdot2) does each 8-dot in 4 VALU ops
//    vs 17 for bf16 unpack. f16 also has MORE mantissa than bf16 -> absmax
//    improves. Guarded by __has_builtin with scalar fallback.
//  - Execution config: one block per batch element, TPB=256,
//    __launch_bounds__(256,1) (measured law: VGPR cap = 256/second_arg).
//  - Floor: 5 W-sweeps x 2.95 MB from L2 per CU ~ 102 us at 144 GB/s/CU.

#define NCLS   10
#define NCAPS  1152
#define KDO    16
#define NIT    3
#define TPB    256
#define NJ     5
#define NWAVE  (TPB / 64)
#define BPAD   11            // blog LDS row stride (words): gcd(11,32)=1 -> 2-way max

typedef _Float16 h2_t __attribute__((ext_vector_type(2)));

static __device__ __forceinline__ unsigned pack2h(float a, float b) {
    union { _Float16 h[2]; unsigned u; } p;
    p.h[0] = (_Float16)a;
    p.h[1] = (_Float16)b;
    return p.u;
}

static __device__ __forceinline__ float dot8h(uint4 r, const unsigned* xh) {
    union { unsigned u; h2_t h; } w0, w1, w2, w3, a0, a1, a2, a3;
    w0.u = r.x; w1.u = r.y; w2.u = r.z; w3.u = r.w;
    a0.u = xh[0]; a1.u = xh[1]; a2.u = xh[2]; a3.u = xh[3];
#if __has_builtin(__builtin_amdgcn_fdot2)
    float acc = __builtin_amdgcn_fdot2(w0.h, a0.h, 0.f, false);
    acc = __builtin_amdgcn_fdot2(w1.h, a1.h, acc, false);
    acc = __builtin_amdgcn_fdot2(w2.h, a2.h, acc, false);
    acc = __builtin_amdgcn_fdot2(w3.h, a3.h, acc, false);
    return acc;
#else
    return (float)w0.h.x * (float)a0.h.x + (float)w0.h.y * (float)a0.h.y
         + (float)w1.h.x * (float)a1.h.x + (float)w1.h.y * (float)a1.h.y
         + (float)w2.h.x * (float)a2.h.x + (float)w2.h.y * (float)a2.h.y
         + (float)w3.h.x * (float)a3.h.x + (float)w3.h.y * (float)a3.h.y;
#endif
}

static __device__ __forceinline__ float dot_f8(const float4* W4, size_t row2,
                                               const float4& x0, const float4& x1) {
    float4 w0 = W4[row2];
    float4 w1 = W4[row2 + 1];
    return w0.x * x0.x + w0.y * x0.y + w0.z * x0.z + w0.w * x0.w
         + w1.x * x1.x + w1.y * x1.y + w1.z * x1.z + w1.w * x1.w;
}

// Wt[c][d][i] : uint4 holding f16 W[c,i,0,d,k] for k=0..7
__global__ __launch_bounds__(256)
void pack_W_f16(const float4* __restrict__ W4, uint4* __restrict__ Wt) {
    int tid = blockIdx.x * blockDim.x + threadIdx.x;   // (c*NCAPS+i)*KDO + d
    if (tid >= NCLS * NCAPS * KDO) return;
    int d = tid & 15;
    int rest = tid >> 4;
    int i = rest % NCAPS;
    int c = rest / NCAPS;
    float4 a = W4[2 * tid];
    float4 b = W4[2 * tid + 1];
    uint4 o;
    o.x = pack2h(a.x, a.y);
    o.y = pack2h(a.z, a.w);
    o.z = pack2h(b.x, b.y);
    o.w = pack2h(b.z, b.w);
    Wt[(size_t)(c * KDO + d) * NCAPS + i] = o;
}

template <bool TR>
__global__ __launch_bounds__(TPB, 1)      // cap = 256/1 = 256 VGPRs (measured law)
void caps_routing(const uint4* __restrict__ Wt,   // TR: [C][KDO][I] f16x8
                  const float4* __restrict__ W4,  // fallback: [C][I][KDO][8] fp32
                  const float* __restrict__ x,    // [B, I, 8]
                  float* __restrict__ out)        // [B, C, 1, KDO]
{
    const int b    = blockIdx.x;
    const int t    = threadIdx.x;
    const int lane = t & 63;
    const int wave = t >> 6;

    __shared__ float blogL[NCAPS * BPAD];            // 50688 B, thread-private slots
    __shared__ float v_prev[NCLS * KDO];             // 640 B
    __shared__ float red[NCLS * NWAVE * KDO];        // 2560 B

    // ---- x[b, ii, :] in registers; fp32 copy (fallback) + f16-packed ----
    float4 xr[NJ][2];
    unsigned xh[NJ][4];
    const float4* x4 = reinterpret_cast<const float4*>(x) + (size_t)b * NCAPS * 2;
    #pragma unroll
    for (int j = 0; j < NJ; ++j) {
        int ii = t + TPB * j;
        if (ii < NCAPS) {
            float4 x0 = x4[2 * ii];
            float4 x1 = x4[2 * ii + 1];
            xr[j][0] = x0; xr[j][1] = x1;
            xh[j][0] = pack2h(x0.x, x0.y);
            xh[j][1] = pack2h(x0.z, x0.w);
            xh[j][2] = pack2h(x1.x, x1.y);
            xh[j][3] = pack2h(x1.z, x1.w);
        }
    }

    // ---- zero blog (thread-private region; no sync needed) ----
    #pragma unroll
    for (int j = 0; j < NJ; ++j) {
        int ii = t + TPB * j;
        if (ii < NCAPS)
            #pragma unroll
            for (int c = 0; c < NCLS; ++c)
                blogL[ii * BPAD + c] = 0.f;
    }

    for (int it = 0; it < NIT; ++it) {
        // ---- Phase A: blog[ii][c] += <u_hat[c,ii,:], v_prev[c,:]> ----
        if (it > 0) {
            #pragma unroll 1                         // runtime c: small body, low regs
            for (int c = 0; c < NCLS; ++c) {
                float vp[KDO];
                #pragma unroll
                for (int d = 0; d < KDO; ++d)
                    vp[d] = v_prev[c * KDO + d];     // LDS broadcast
                #pragma unroll
                for (int j = 0; j < NJ; ++j) {
                    int ii = t + TPB * j;
                    if (ii < NCAPS) {
                        float a = 0.f;
                        #pragma unroll
                        for (int d = 0; d < KDO; ++d) {
                            float u = TR ? dot8h(Wt[(size_t)(c * KDO + d) * NCAPS + ii], xh[j])
                                         : dot_f8(W4, ((size_t)(c * NCAPS + ii) * KDO + d) * 2,
                                                  xr[j][0], xr[j][1]);
                            a += u * vp[d];
                        }
                        blogL[ii * BPAD + c] += a;
                    }
                }
            }
        }

        // ---- Phase B: softmax over classes (per-capsule, own LDS slots) ----
        float sm[NJ], sid[NJ];
        #pragma unroll
        for (int j = 0; j < NJ; ++j) {
            int ii = t + TPB * j;
            if (ii < NCAPS) {
                float bl[NCLS];
                #pragma unroll
                for (int c = 0; c < NCLS; ++c) bl[c] = blogL[ii * BPAD + c];
                float m = bl[0];
                #pragma unroll
                for (int c = 1; c < NCLS; ++c) m = fmaxf(m, bl[c]);
                float den = 0.f;
                #pragma unroll
                for (int c = 0; c < NCLS; ++c) den += __expf(bl[c] - m);
                sm[j]  = m;
                sid[j] = 1.f / den;
            }
        }

        // ---- Phase C: s[c,:] = sum_ii softmax_c(blog) * u_hat[c,ii,:] ----
        #pragma unroll 1                             // runtime c
        for (int c = 0; c < NCLS; ++c) {
            float acc[KDO];
            #pragma unroll
            for (int d = 0; d < KDO; ++d) acc[d] = 0.f;

            #pragma unroll
            for (int j = 0; j < NJ; ++j) {
                int ii = t + TPB * j;
                if (ii < NCAPS) {
                    float wgt = __expf(blogL[ii * BPAD + c] - sm[j]) * sid[j];
                    #pragma unroll
                    for (int d = 0; d < KDO; ++d) {
                        float u = TR ? dot8h(Wt[(size_t)(c * KDO + d) * NCAPS + ii], xh[j])
                                     : dot_f8(W4, ((size_t)(c * NCAPS + ii) * KDO + d) * 2,
                                              xr[j][0], xr[j][1]);
                        acc[d] += wgt * u;
                    }
                }
            }

            #pragma unroll
            for (int d = 0; d < KDO; ++d) {
                float v = acc[d];
                v += __shfl_xor(v, 32, 64);
                v += __shfl_xor(v, 16, 64);
                v += __shfl_xor(v,  8, 64);
                v += __shfl_xor(v,  4, 64);
                v += __shfl_xor(v,  2, 64);
                v += __shfl_xor(v,  1, 64);
                if (lane == 0) red[(c * NWAVE + wave) * KDO + d] = v;
            }
        }
        __syncthreads();

        // ---- squash + broadcast: threads 0..159 (c = t/16, d = t%16) ----
        if (t < NCLS * KDO) {
            int c = t >> 4;
            int d = t & 15;
            float s = 0.f;
            #pragma unroll
            for (int w = 0; w < NWAVE; ++w)
                s += red[(c * NWAVE + w) * KDO + d];
            float nsq = s * s;
            nsq += __shfl_xor(nsq, 8, 16);
            nsq += __shfl_xor(nsq, 4, 16);
            nsq += __shfl_xor(nsq, 2, 16);
            nsq += __shfl_xor(nsq, 1, 16);
            float scale = sqrtf(nsq) / (1.f + nsq);  // (nsq/(1+nsq))/sqrt(nsq)
            float vv = s * scale;
            v_prev[t] = vv;
            if (it == NIT - 1)
                out[(size_t)b * NCLS * KDO + t] = vv;
        }
        __syncthreads();
    }
}

extern "C" void kernel_launch(void* const* d_in, const int* in_sizes, int n_in,
                              void* d_out, int out_size, void* d_ws, size_t ws_size,
                              hipStream_t stream) {
    const float* x = (const float*)d_in[0];              // [256, 1152, 8] fp32
    const float4* W4 = (const float4*)d_in[1];           // [10, 1152, 1, 16, 8] fp32
    float* out = (float*)d_out;                          // [256, 10, 1, 16] fp32
    (void)in_sizes; (void)n_in; (void)out_size;

    const int B = 256;
    const size_t wt_bytes = (size_t)NCLS * KDO * NCAPS * sizeof(uint4);  // 2.95 MB
    if (ws_size >= wt_bytes) {
        uint4* Wt = (uint4*)d_ws;
        int total = NCLS * NCAPS * KDO;
        pack_W_f16<<<dim3((total + 255) / 256), dim3(256), 0, stream>>>(W4, Wt);
        caps_routing<true><<<dim3(B), dim3(TPB), 0, stream>>>(Wt, W4, x, out);
    } else {
        caps_routing<false><<<dim3(B), dim3(TPB), 0, stream>>>(nullptr, W4, x, out);
    }
}

// Round 8
// 401.100 us; speedup vs baseline: 5.6889x; 1.7654x over previous
//
#include <hip/hip_runtime.h>

// DigitCapsules dynamic routing. Round-8 design:
//  - ALGORITHMIC: W sweeps cut 5 -> 3. s[c]/v[c] depend only on class c, so
//    each iteration processes classes sequentially: one W[c]-sweep computes
//    u_hat (kept packed-f16 in registers, 24 VGPRs), C-accumulates, block-
//    reduces s[c], squashes v[c], then does the agreement update
//    blog[i][c] += <u,v[c]> from the REGISTER copy of u -- Phase A's W
//    re-sweep is gone. L2 traffic 14.75 -> 8.85 MB/CU; aggregate floor
//    2.27 GB / 34.5 TB/s ~ 66 us.
//  - TPB=512 (__launch_bounds__(512,1)): 2 waves/SIMD (R7 ran 1 wave/SIMD,
//    VALUBusy 8.5%, pure vmcnt latency). Register footprint kept lean
//    (~95: packed-f16 u and x) so even a 128-VGPR cap wouldn't spill.
//  - Keeps R7's proven pieces: blog in LDS (thread-private slots, BPAD=11
//    -> 2-way bank aliasing = free), runtime class loop (#pragma unroll 1),
//    f16-packed transposed Wt[c][d][i] uint4 + v_dot2_f32_f16.

#define NCLS   10
#define NCAPS  1152
#define KDO    16
#define NIT    3
#define TPB    512
#define NJ     3
#define NWAVE  (TPB / 64)
#define BPAD   11

typedef _Float16 h2_t __attribute__((ext_vector_type(2)));

static __device__ __forceinline__ unsigned pack2h(float a, float b) {
    union { _Float16 h[2]; unsigned u; } p;
    p.h[0] = (_Float16)a;
    p.h[1] = (_Float16)b;
    return p.u;
}

static __device__ __forceinline__ float dot8h(uint4 r, const unsigned* xh) {
    union { unsigned u; h2_t h; } w0, w1, w2, w3, a0, a1, a2, a3;
    w0.u = r.x; w1.u = r.y; w2.u = r.z; w3.u = r.w;
    a0.u = xh[0]; a1.u = xh[1]; a2.u = xh[2]; a3.u = xh[3];
#if __has_builtin(__builtin_amdgcn_fdot2)
    float acc = __builtin_amdgcn_fdot2(w0.h, a0.h, 0.f, false);
    acc = __builtin_amdgcn_fdot2(w1.h, a1.h, acc, false);
    acc = __builtin_amdgcn_fdot2(w2.h, a2.h, acc, false);
    acc = __builtin_amdgcn_fdot2(w3.h, a3.h, acc, false);
    return acc;
#else
    return (float)w0.h.x * (float)a0.h.x + (float)w0.h.y * (float)a0.h.y
         + (float)w1.h.x * (float)a1.h.x + (float)w1.h.y * (float)a1.h.y
         + (float)w2.h.x * (float)a2.h.x + (float)w2.h.y * (float)a2.h.y
         + (float)w3.h.x * (float)a3.h.x + (float)w3.h.y * (float)a3.h.y;
#endif
}

static __device__ __forceinline__ float dot2h(unsigned a, unsigned b, float acc) {
    union { unsigned u; h2_t h; } pa, pb;
    pa.u = a; pb.u = b;
#if __has_builtin(__builtin_amdgcn_fdot2)
    return __builtin_amdgcn_fdot2(pa.h, pb.h, acc, false);
#else
    return acc + (float)pa.h.x * (float)pb.h.x + (float)pa.h.y * (float)pb.h.y;
#endif
}

static __device__ __forceinline__ float dot_f8(const float4* W4, size_t row2,
                                               const float4& x0, const float4& x1) {
    float4 w0 = W4[row2];
    float4 w1 = W4[row2 + 1];
    return w0.x * x0.x + w0.y * x0.y + w0.z * x0.z + w0.w * x0.w
         + w1.x * x1.x + w1.y * x1.y + w1.z * x1.z + w1.w * x1.w;
}

// Wt[c][d][i] : uint4 holding f16 W[c,i,0,d,k] for k=0..7
__global__ __launch_bounds__(256)
void pack_W_f16(const float4* __restrict__ W4, uint4* __restrict__ Wt) {
    int tid = blockIdx.x * blockDim.x + threadIdx.x;   // (c*NCAPS+i)*KDO + d
    if (tid >= NCLS * NCAPS * KDO) return;
    int d = tid & 15;
    int rest = tid >> 4;
    int i = rest % NCAPS;
    int c = rest / NCAPS;
    float4 a = W4[2 * tid];
    float4 b = W4[2 * tid + 1];
    uint4 o;
    o.x = pack2h(a.x, a.y);
    o.y = pack2h(a.z, a.w);
    o.z = pack2h(b.x, b.y);
    o.w = pack2h(b.z, b.w);
    Wt[(size_t)(c * KDO + d) * NCAPS + i] = o;
}

template <bool TR>
__global__ __launch_bounds__(TPB, 1)
void caps_routing(const uint4* __restrict__ Wt,   // TR: [C][KDO][I] f16x8
                  const float4* __restrict__ W4,  // fallback: [C][I][KDO][8] fp32
                  const float* __restrict__ x,    // [B, I, 8]
                  float* __restrict__ out)        // [B, C, 1, KDO]
{
    const int b    = blockIdx.x;
    const int t    = threadIdx.x;
    const int lane = t & 63;
    const int wave = t >> 6;

    __shared__ float blogL[NCAPS * BPAD];            // 50688 B, thread-private slots
    __shared__ float red[NWAVE * KDO];               // 512 B (per-class scratch)
    __shared__ float vsh[KDO];                       // 64 B  (per-class v)

    // ---- x[b, ii, :]: f16-packed (TR) + fp32 copy (fallback; DCE'd if TR) ----
    float4 xr[NJ][2];
    unsigned xh[NJ][4];
    const float4* x4 = reinterpret_cast<const float4*>(x) + (size_t)b * NCAPS * 2;
    #pragma unroll
    for (int j = 0; j < NJ; ++j) {
        int ii = t + TPB * j;
        if (ii < NCAPS) {
            float4 x0 = x4[2 * ii];
            float4 x1 = x4[2 * ii + 1];
            xr[j][0] = x0; xr[j][1] = x1;
            xh[j][0] = pack2h(x0.x, x0.y);
            xh[j][1] = pack2h(x0.z, x0.w);
            xh[j][2] = pack2h(x1.x, x1.y);
            xh[j][3] = pack2h(x1.z, x1.w);
        }
    }

    // ---- zero blog (thread-private; no sync needed) ----
    #pragma unroll
    for (int j = 0; j < NJ; ++j) {
        int ii = t + TPB * j;
        if (ii < NCAPS)
            #pragma unroll
            for (int c = 0; c < NCLS; ++c)
                blogL[ii * BPAD + c] = 0.f;
    }

    for (int it = 0; it < NIT; ++it) {
        // ---- softmax over classes per capsule (own LDS slots) ----
        float sm[NJ], sid[NJ];
        #pragma unroll
        for (int j = 0; j < NJ; ++j) {
            int ii = t + TPB * j;
            if (ii < NCAPS) {
                float bl[NCLS];
                #pragma unroll
                for (int c = 0; c < NCLS; ++c) bl[c] = blogL[ii * BPAD + c];
                float m = bl[0];
                #pragma unroll
                for (int c = 1; c < NCLS; ++c) m = fmaxf(m, bl[c]);
                float den = 0.f;
                #pragma unroll
                for (int c = 0; c < NCLS; ++c) den += __expf(bl[c] - m);
                sm[j]  = m;
                sid[j] = 1.f / den;
            }
        }

        // ---- per-class: one W[c] sweep -> u (regs) -> s[c] -> v[c] -> blog ----
        #pragma unroll 1                             // runtime c: small body
        for (int c = 0; c < NCLS; ++c) {
            unsigned upk[NJ][8];                     // u_hat packed f16 (24 regs)
            float acc[KDO];
            #pragma unroll
            for (int d = 0; d < KDO; ++d) acc[d] = 0.f;

            #pragma unroll
            for (int j = 0; j < NJ; ++j) {
                int ii = t + TPB * j;
                if (ii < NCAPS) {
                    float wgt = __expf(blogL[ii * BPAD + c] - sm[j]) * sid[j];
                    #pragma unroll
                    for (int dp = 0; dp < 8; ++dp) {
                        int d0 = 2 * dp, d1 = 2 * dp + 1;
                        float u0, u1;
                        if (TR) {
                            u0 = dot8h(Wt[(size_t)(c * KDO + d0) * NCAPS + ii], xh[j]);
                            u1 = dot8h(Wt[(size_t)(c * KDO + d1) * NCAPS + ii], xh[j]);
                        } else {
                            u0 = dot_f8(W4, ((size_t)(c * NCAPS + ii) * KDO + d0) * 2,
                                        xr[j][0], xr[j][1]);
                            u1 = dot_f8(W4, ((size_t)(c * NCAPS + ii) * KDO + d1) * 2,
                                        xr[j][0], xr[j][1]);
                        }
                        acc[d0] += wgt * u0;
                        acc[d1] += wgt * u1;
                        upk[j][dp] = pack2h(u0, u1);   // keep u for agreement update
                    }
                }
            }

            // block-reduce acc -> red
            #pragma unroll
            for (int d = 0; d < KDO; ++d) {
                float v = acc[d];
                v += __shfl_xor(v, 32, 64);
                v += __shfl_xor(v, 16, 64);
                v += __shfl_xor(v,  8, 64);
                v += __shfl_xor(v,  4, 64);
                v += __shfl_xor(v,  2, 64);
                v += __shfl_xor(v,  1, 64);
                if (lane == 0) red[wave * KDO + d] = v;
            }
            __syncthreads();

            // squash s[c] -> v[c]: threads 0..15 (d = t)
            if (t < KDO) {
                float s = 0.f;
                #pragma unroll
                for (int w = 0; w < NWAVE; ++w) s += red[w * KDO + t];
                float nsq = s * s;
                nsq += __shfl_xor(nsq, 8, 16);
                nsq += __shfl_xor(nsq, 4, 16);
                nsq += __shfl_xor(nsq, 2, 16);
                nsq += __shfl_xor(nsq, 1, 16);
                float scale = sqrtf(nsq) / (1.f + nsq);  // (nsq/(1+nsq))/sqrt(nsq)
                float vv = s * scale;
                vsh[t] = vv;
                if (it == NIT - 1)
                    out[(size_t)b * NCLS * KDO + c * KDO + t] = vv;
            }
            __syncthreads();

            // agreement update from REGISTER u (no W re-sweep)
            if (it < NIT - 1) {
                unsigned vp[8];
                #pragma unroll
                for (int dp = 0; dp < 8; ++dp)
                    vp[dp] = pack2h(vsh[2 * dp], vsh[2 * dp + 1]);
                #pragma unroll
                for (int j = 0; j < NJ; ++j) {
                    int ii = t + TPB * j;
                    if (ii < NCAPS) {
                        float a = 0.f;
                        #pragma unroll
                        for (int dp = 0; dp < 8; ++dp)
                            a = dot2h(upk[j][dp], vp[dp], a);
                        blogL[ii * BPAD + c] += a;
                    }
                }
            }
            // next chunk's red writes happen after this barrier pair -> safe
        }
    }
}

extern "C" void kernel_launch(void* const* d_in, const int* in_sizes, int n_in,
                              void* d_out, int out_size, void* d_ws, size_t ws_size,
                              hipStream_t stream) {
    const float* x = (const float*)d_in[0];              // [256, 1152, 8] fp32
    const float4* W4 = (const float4*)d_in[1];           // [10, 1152, 1, 16, 8] fp32
    float* out = (float*)d_out;                          // [256, 10, 1, 16] fp32
    (void)in_sizes; (void)n_in; (void)out_size;

    const int B = 256;
    const size_t wt_bytes = (size_t)NCLS * KDO * NCAPS * sizeof(uint4);  // 2.95 MB
    if (ws_size >= wt_bytes) {
        uint4* Wt = (uint4*)d_ws;
        int total = NCLS * NCAPS * KDO;
        pack_W_f16<<<dim3((total + 255) / 256), dim3(256), 0, stream>>>(W4, Wt);
        caps_routing<true><<<dim3(B), dim3(TPB), 0, stream>>>(Wt, W4, x, out);
    } else {
        caps_routing<false><<<dim3(B), dim3(TPB), 0, stream>>>(nullptr, W4, x, out);
    }
}